// Round 9
// baseline (1727.351 us; speedup 1.0000x reference)
//
#include <hip/hip_runtime.h>
#include <stdint.h>

// W8A16 quantized linear, two-phase:
//   Pre-pass: A f32->f16 (64 MB), W = fp16(q*scale) (32 MB) into d_ws.
//   GEMM:     block 256x512, BK=32, 8 waves (2M x 4N), wave tile 128x128
//             (acc[8][8] -> LDS-read/FLOP ratio 0.62 vs 0.93 at 128x64),
//             4 phases/K-tile, counted vmcnt, raw s_barrier, setprio.
//   LDS packing: two logical rows per 128-B LDS row; 16-B slot
//             p = ((r&1)*4 | s) ^ ((r>>1)&7)  -> 2-way bank access (free).
//             Stage via global_load_lds(16B) linear dest + inverse-swizzled
//             global source; reads apply the same XOR (rule-21 both-sides).
// R8 bug fixed here: LDS arrays were declared HALF size (BM*BK/2) -> staging
// overflowed As into Bs and Bs past the allocation. Correct: As 8192 f16/buf
// (16 KB), Bs 16384 f16/buf (32 KB), 96 KB total.
// Ledger (units of 2 vm-insts; stages at p1:A', p2:B0', p3:B1'):
//   entering p1(kt): outstanding=[B1(kt)]; p1 issues A' ->4, vmcnt(2)
//   retires B1(kt) (slack 2 phases) sealing p2's B1 reads; p2 issues B0'
//   ->4; p3 issues B1' ->6; p4 vmcnt(2) retires A',B0' (slack 2-3) sealing
//   p1(kt+1)'s reads. Prologue: stage A,B0,B1(0), vmcnt(2). Tail: vmcnt(0).

#define M_DIM 8192
#define N_DIM 4096
#define K_DIM 4096
#define BM 256
#define BN 512
#define BK 32
#define NKT (K_DIM / BK)   // 128 K-tiles

typedef _Float16 f16;
typedef f16 f16x8 __attribute__((ext_vector_type(8)));
typedef f16 f16x2 __attribute__((ext_vector_type(2)));
typedef float f32x4 __attribute__((ext_vector_type(4)));

static __device__ __forceinline__ f16x2 cvt2(float a, float b) {
  return __builtin_bit_cast(f16x2, __builtin_amdgcn_cvt_pkrtz(a, b));
}

// ---------------- pre-pass kernels ----------------

__global__ __launch_bounds__(256) void conv_a_kernel(
    const float* __restrict__ A, f16* __restrict__ Af)
{
  const size_t stride = (size_t)gridDim.x * blockDim.x;
  size_t i = (size_t)blockIdx.x * blockDim.x + threadIdx.x;
  const size_t n8 = (size_t)M_DIM * K_DIM / 8;
  for (; i < n8; i += stride) {
    const f32x4* p = (const f32x4*)(A + i * 8);
    f32x4 v0 = p[0], v1 = p[1];
    f16x2 a = cvt2(v0.x, v0.y), b = cvt2(v0.z, v0.w);
    f16x2 c = cvt2(v1.x, v1.y), d = cvt2(v1.z, v1.w);
    *(f16x8*)(Af + i * 8) = (f16x8){a.x, a.y, b.x, b.y, c.x, c.y, d.x, d.y};
  }
}

__global__ __launch_bounds__(256) void conv_b_kernel(
    const int* __restrict__ Qw, const float* __restrict__ Sc,
    f16* __restrict__ Wf)
{
  const int o = blockIdx.x;
  const int t = threadIdx.x;
  const float s = Sc[o];
  const int* q = Qw + (size_t)o * K_DIM + t * 16;
  f16* w = Wf + (size_t)o * K_DIM + t * 16;
  #pragma unroll
  for (int h = 0; h < 2; ++h) {
    int4 u0 = *(const int4*)(q + h * 8);
    int4 u1 = *(const int4*)(q + h * 8 + 4);
    f16x2 a = cvt2((float)u0.x * s, (float)u0.y * s);
    f16x2 b = cvt2((float)u0.z * s, (float)u0.w * s);
    f16x2 c = cvt2((float)u1.x * s, (float)u1.y * s);
    f16x2 d = cvt2((float)u1.z * s, (float)u1.w * s);
    *(f16x8*)(w + h * 8) = (f16x8){a.x, a.y, b.x, b.y, c.x, c.y, d.x, d.y};
  }
}

// ---------------- main GEMM ----------------

#define BARX() __builtin_amdgcn_s_barrier()
#define SCHED0() __builtin_amdgcn_sched_barrier(0)
#define LGKM0() do { asm volatile("s_waitcnt lgkmcnt(0)" ::: "memory"); \
                     __builtin_amdgcn_sched_barrier(0); } while (0)
#define VMW(n) asm volatile("s_waitcnt vmcnt(" #n ")" ::: "memory")

// read 4 A-frags (m-half) into af[0..3]
#define READ_A(half) do { \
  _Pragma("unroll") \
  for (int m = 0; m < 4; ++m) \
    af[m] = *(const f16x8*)(abase + a_rd[(half) * 4 + m]); \
  } while (0)

// read 4 B-frags (n-half) into bf[0..3]
#define READ_B(half, bf) do { \
  _Pragma("unroll") \
  for (int n = 0; n < 4; ++n) \
    bf[n] = *(const f16x8*)(bbase + b_rd[(half) * 4 + n]); \
  } while (0)

// 16 MFMA for quadrant (qm, qn): all independent accumulators
#define MFMAQ(qm, qn, bf) do { \
  __builtin_amdgcn_s_setprio(1); \
  _Pragma("unroll") \
  for (int m = 0; m < 4; ++m) \
    _Pragma("unroll") \
    for (int n = 0; n < 4; ++n) \
      acc[(qm) * 4 + m][(qn) * 4 + n] = __builtin_amdgcn_mfma_f32_16x16x32_f16( \
          af[m], bf[n], acc[(qm) * 4 + m][(qn) * 4 + n], 0, 0, 0); \
  __builtin_amdgcn_s_setprio(0); } while (0)

// stage A tile (256x32 f16 = 16 KB = 2 issues); packed-pair + inv-swizzle src
#define STAGE_A(buf_, ktn) do { \
  _Pragma("unroll") \
  for (int _i = 0; _i < 2; ++_i) { \
    const f16* _g = aSrc + (size_t)((st_R + 64 * _i) * 2 + st_h) * K_DIM \
                    + (ktn) * 32 + st_s * 8; \
    char* _l = (char*)&As[buf_][0] + _i * 8192 + wid * 1024; \
    __builtin_amdgcn_global_load_lds( \
        (const __attribute__((address_space(1))) void*)_g, \
        (__attribute__((address_space(3))) void*)_l, 16, 0, 0); \
  } } while (0)

// stage B half (256x32 f16 = 16 KB = 2 issues)
#define STAGE_B(buf_, half, ktn) do { \
  _Pragma("unroll") \
  for (int _i = 0; _i < 2; ++_i) { \
    const f16* _g = bSrc + (size_t)(((half) * 128 + st_R + 64 * _i) * 2 + st_h) * K_DIM \
                    + (ktn) * 32 + st_s * 8; \
    char* _l = (char*)&Bs[buf_][0] + (half) * 16384 + _i * 8192 + wid * 1024; \
    __builtin_amdgcn_global_load_lds( \
        (const __attribute__((address_space(1))) void*)_g, \
        (__attribute__((address_space(3))) void*)_l, 16, 0, 0); \
  } } while (0)

__global__ __launch_bounds__(512) void w8a16_gemm_f16_kernel(
    const f16* __restrict__ Af,   // [M][K]
    const f16* __restrict__ Wf,   // [N][K], scale folded
    float* __restrict__ Out)      // [M][N]
{
  // A: 8192 f16 (16 KB) per buffer; B: 16384 f16 (32 KB) per buffer. 96 KB.
  __shared__ __align__(16) f16 As[2][BM * BK];   // [2][8192]
  __shared__ __align__(16) f16 Bs[2][BN * BK];   // [2][16384]

  const int t    = threadIdx.x;
  const int lane = t & 63;
  const int wid  = t >> 6;       // 0..7
  const int wm   = wid >> 2;     // 0..1  (M interleave)
  const int wn   = wid & 3;      // 0..3  (N interleave)
  const int fr   = lane & 15;
  const int qk   = lane >> 4;    // k-slot 0..3

  // staging map: thread t -> LDS-row R=t>>3, phys slot p=t&7;
  // logical: x = p ^ (R&7) -> half h = x>>2, k-slot s = x&3.
  const int st_R = t >> 3;
  const int st_x = (t & 7) ^ (st_R & 7);
  const int st_h = st_x >> 2;
  const int st_s = st_x & 3;

  // read addrs: logical row r, slot qk -> byte (r>>1)*128 + ((((r&1)<<2)|qk)^((r>>1)&7))*16
  int a_rd[8], b_rd[8];
  #pragma unroll
  for (int f = 0; f < 8; ++f) {
    const int ra = (2 * f + wm) * 16 + fr;
    const int Ra = ra >> 1;
    a_rd[f] = Ra * 128 + (((((ra & 1) << 2) | qk) ^ (Ra & 7)) << 4);
    const int rb = (4 * f + wn) * 16 + fr;
    const int Rb = rb >> 1;
    b_rd[f] = Rb * 128 + (((((rb & 1) << 2) | qk) ^ (Rb & 7)) << 4);
  }

  // XCD swizzle: 256 blocks; tn = swz>>5 -> one 4 MB B-panel per XCD (= L2)
  const int bid = blockIdx.x;
  const int swz = (bid & 7) * 32 + (bid >> 3);
  const int tm  = swz & 31;      // 32 M-tiles
  const int tn  = swz >> 5;      // 8 N-tiles

  const f16* aSrc = Af + (size_t)tm * BM * K_DIM;
  const f16* bSrc = Wf + (size_t)tn * BN * K_DIM;

  f32x4 acc[8][8] = {};
  f16x8 af[4], bf0[4], bf1[4];

  // prologue: stage A(0), B0(0), B1(0); confirm A,B0; leave [B1(0)]
  STAGE_A(0, 0);
  STAGE_B(0, 0, 0);
  STAGE_B(0, 1, 0);
  VMW(2);
  BARX();
  SCHED0();

  for (int kt = 0; kt < NKT; ++kt) {
    const int  buf  = kt & 1;
    const int  nbuf = buf ^ 1;
    const bool more = (kt + 1) < NKT;
    const char* abase = (const char*)&As[buf][0];
    const char* bbase = (const char*)&Bs[buf][0];

    // p1: (A0,B0); issue A'; retire B1(kt)
    READ_A(0);
    READ_B(0, bf0);
    if (more) { STAGE_A(nbuf, kt + 1); VMW(2); } else VMW(0);
    BARX(); LGKM0();
    MFMAQ(0, 0, bf0);
    BARX();

    // p2: (A0,B1); issue B0'
    READ_B(1, bf1);
    if (more) STAGE_B(nbuf, 0, kt + 1);
    BARX(); LGKM0();
    MFMAQ(0, 1, bf1);
    BARX();

    // p3: (A1,B1); issue B1'
    READ_A(1);
    if (more) STAGE_B(nbuf, 1, kt + 1);
    BARX(); LGKM0();
    MFMAQ(1, 1, bf1);
    BARX();

    // p4: (A1,B0) reg-reuse; retire A',B0'
    if (more) VMW(2);
    BARX(); LGKM0();
    MFMAQ(1, 0, bf0);
    BARX();
  }

  // epilogue: C/D col = lane&15, row = (lane>>4)*4 + reg
  const int fq = lane >> 4;
  #pragma unroll
  for (int mi = 0; mi < 8; ++mi) {
    const size_t row = (size_t)tm * BM + (2 * mi + wm) * 16 + fq * 4;
    #pragma unroll
    for (int ni = 0; ni < 8; ++ni) {
      const size_t col = (size_t)tn * BN + (4 * ni + wn) * 16 + fr;
      #pragma unroll
      for (int r = 0; r < 4; ++r)
        Out[(row + r) * N_DIM + col] = acc[mi][ni][r];
    }
  }
}

// ---------------- fallback (round-3 verified path) ----------------

__global__ __launch_bounds__(256) void w8a16_gemm_fb_kernel(
    const float* __restrict__ A, const int* __restrict__ Qw,
    const float* __restrict__ Sc, float* __restrict__ Out)
{
  __shared__ __align__(16) float Asf[2][128 * 32];
  __shared__ __align__(16) f16 Bsf[2][128][32];

  const int t = threadIdx.x, lane = t & 63, wid = t >> 6;
  const int wr = wid >> 1, wc = wid & 1;
  const int nwg = gridDim.x, cpx = nwg >> 3, bid = blockIdx.x;
  const int swz = (bid & 7) * cpx + (bid >> 3);
  const int tn = swz & 31, tm = swz >> 5;
  const size_t a_base = (size_t)tm * 128 * K_DIM;
  const size_t b_base = (size_t)tn * 128 * K_DIM;
  f32x4 acc[4][4] = {};
  const int a_r = t >> 3;
  const int a_slog = (t & 7) ^ ((t >> 3) & 7);

  auto stageA = [&](int buf, int kt) {
    #pragma unroll
    for (int c = 0; c < 4; ++c) {
      const float* g = A + a_base + (size_t)(c * 32 + a_r) * K_DIM + kt * 32 + a_slog * 4;
      char* l = (char*)&Asf[buf][0] + c * 4096 + wid * 1024;
      __builtin_amdgcn_global_load_lds(
          (const __attribute__((address_space(1))) void*)g,
          (__attribute__((address_space(3))) void*)l, 16, 0, 0);
    }
  };
  const int b_r = t >> 3, b_col = (t & 7) * 4;
  auto loadB = [&](int kt, int4* v) {
    #pragma unroll
    for (int c = 0; c < 4; ++c)
      v[c] = *(const int4*)(Qw + b_base + (size_t)(c * 32 + b_r) * K_DIM + kt * 32 + b_col);
  };
  auto writeB = [&](int buf, const int4* v) {
    #pragma unroll
    for (int c = 0; c < 4; ++c) {
      f16x2 lo = cvt2((float)v[c].x, (float)v[c].y);
      f16x2 hi = cvt2((float)v[c].z, (float)v[c].w);
      *(f16x2*)&Bsf[buf][c * 32 + b_r][b_col] = lo;
      *(f16x2*)&Bsf[buf][c * 32 + b_r][b_col + 2] = hi;
    }
  };
  auto compute = [&](int buf) {
    const int fr2 = lane & 15, q = lane >> 4;
    f16x8 af2[4], bf2[4];
    #pragma unroll
    for (int i = 0; i < 4; ++i) {
      const int r = wr * 64 + i * 16 + fr2;
      const float* base = &Asf[buf][0] + r * 32;
      const int s0 = q * 2;
      f32x4 a0 = *(const f32x4*)(base + ((s0 ^ (r & 7)) * 4));
      f32x4 a1 = *(const f32x4*)(base + (((s0 + 1) ^ (r & 7)) * 4));
      f16x2 p0 = cvt2(a0.x, a0.y), p1 = cvt2(a0.z, a0.w);
      f16x2 p2 = cvt2(a1.x, a1.y), p3 = cvt2(a1.z, a1.w);
      af2[i] = (f16x8){p0.x, p0.y, p1.x, p1.y, p2.x, p2.y, p3.x, p3.y};
      bf2[i] = *(const f16x8*)&Bsf[buf][wc * 64 + i * 16 + fr2][q * 8];
    }
    #pragma unroll
    for (int mi = 0; mi < 4; ++mi)
      #pragma unroll
      for (int ni = 0; ni < 4; ++ni)
        acc[mi][ni] = __builtin_amdgcn_mfma_f32_16x16x32_f16(
            af2[mi], bf2[ni], acc[mi][ni], 0, 0, 0);
  };

  { int4 b0[4]; stageA(0, 0); loadB(0, b0); writeB(0, b0); }
  __syncthreads();
  for (int kt = 0; kt < K_DIM / 32; ++kt) {
    const int buf = kt & 1;
    const bool more = (kt + 1) < K_DIM / 32;
    int4 nb[4];
    if (more) { stageA(buf ^ 1, kt + 1); loadB(kt + 1, nb); }
    compute(buf);
    if (more) writeB(buf ^ 1, nb);
    __syncthreads();
  }
  const int fr2 = lane & 15, fq = lane >> 4;
  const int cb = tn * 128 + wc * 64 + fr2;
  const int rb = tm * 128 + wr * 64 + fq * 4;
  #pragma unroll
  for (int ni = 0; ni < 4; ++ni) {
    const float s = Sc[cb + ni * 16];
    #pragma unroll
    for (int mi = 0; mi < 4; ++mi)
      #pragma unroll
      for (int r = 0; r < 4; ++r)
        Out[(size_t)(rb + mi * 16 + r) * N_DIM + (cb + ni * 16)] =
            acc[mi][ni][r] * s;
  }
}

extern "C" void kernel_launch(void* const* d_in, const int* in_sizes, int n_in,
                              void* d_out, int out_size, void* d_ws, size_t ws_size,
                              hipStream_t stream) {
  const float* A  = (const float*)d_in[0];
  const int*   Qw = (const int*)d_in[1];
  const float* Sc = (const float*)d_in[2];
  float*       Out = (float*)d_out;

  const size_t a_bytes = (size_t)M_DIM * K_DIM * sizeof(f16);  // 64 MB
  const size_t w_bytes = (size_t)N_DIM * K_DIM * sizeof(f16);  // 32 MB

  if (ws_size >= a_bytes + w_bytes) {
    f16* Af = (f16*)d_ws;
    f16* Wf = (f16*)((char*)d_ws + a_bytes);
    conv_a_kernel<<<2048, 256, 0, stream>>>(A, Af);
    conv_b_kernel<<<N_DIM, 256, 0, stream>>>(Qw, Sc, Wf);
    dim3 grid((M_DIM / BM) * (N_DIM / BN));  // 32*8 = 256 blocks = 1/CU
    w8a16_gemm_f16_kernel<<<grid, 512, 0, stream>>>(Af, Wf, Out);
  } else {
    dim3 grid((M_DIM / 128) * (N_DIM / 128));
    w8a16_gemm_fb_kernel<<<grid, 256, 0, stream>>>(A, Qw, Sc, Out);
  }
}

// Round 10
// 283.807 us; speedup vs baseline: 6.0864x; 6.0864x over previous
//
#include <hip/hip_runtime.h>
#include <stdint.h>

// W8A16 quantized linear, two-phase:
//   Pre-pass: A f32->f16 (64 MB), W = fp16(q*scale) (32 MB) into d_ws.
//   GEMM:     256x256 tile, BK=64, 8 waves (2M x 4N), wave tile 128x64
//             (acc[8][4], fits regs), FRAGMENT-PIPELINED 4-phase schedule:
//             phase p+1's ds_reads issue before phase p's MFMA so LDS
//             service overlaps the matrix pipe. Persistent frag buffers
//             af0/af1/bf0/bf1; quadrant order (00),(01),(10),(11) makes
//             every read target distinct from in-use frags, incl. the
//             tile-boundary reads (issued mid-p4 after the seal barrier,
//             hidden under q11). __launch_bounds__(512,2) -> 256-VGPR cap
//             (R9 lesson: default cap 128 spilled acc to scratch, 4 GB wr).
// lgkm ledger (ds_reads, b128 units): enter p1 flight=12 (A0,B0 boundary);
//   p1 +4 (B1) -> lgkm(4); p2 +8 (A1) -> lgkm(8) retires B1;
//   p3 lgkm(0) retires A1; p4 issues 12 boundary reads from nbuf.
// vmcnt ledger (stage insts): p1 issues HA0',HB0',HB1' (6), p2 HA1' (2);
//   seal at p4 = vmcnt(0)+barrier; youngest stage has 2-phase slack.
// buf-reuse race: all reads of buf(kt) complete per-wave at p3's lgkm(0),
//   block-wide at p3's barrier; kt+1 stages into buf(kt) issue after it.

#define M_DIM 8192
#define N_DIM 4096
#define K_DIM 4096
#define BM 256
#define BN 256
#define BK 64
#define NKT (K_DIM / BK)   // 64 K-tiles

typedef _Float16 f16;
typedef f16 f16x8 __attribute__((ext_vector_type(8)));
typedef f16 f16x2 __attribute__((ext_vector_type(2)));
typedef float f32x4 __attribute__((ext_vector_type(4)));

static __device__ __forceinline__ f16x2 cvt2(float a, float b) {
  return __builtin_bit_cast(f16x2, __builtin_amdgcn_cvt_pkrtz(a, b));
}

// ---------------- pre-pass kernels ----------------

__global__ __launch_bounds__(256) void conv_a_kernel(
    const float* __restrict__ A, f16* __restrict__ Af)
{
  const size_t stride = (size_t)gridDim.x * blockDim.x;
  size_t i = (size_t)blockIdx.x * blockDim.x + threadIdx.x;
  const size_t n8 = (size_t)M_DIM * K_DIM / 8;
  for (; i < n8; i += stride) {
    const f32x4* p = (const f32x4*)(A + i * 8);
    f32x4 v0 = p[0], v1 = p[1];
    f16x2 a = cvt2(v0.x, v0.y), b = cvt2(v0.z, v0.w);
    f16x2 c = cvt2(v1.x, v1.y), d = cvt2(v1.z, v1.w);
    *(f16x8*)(Af + i * 8) = (f16x8){a.x, a.y, b.x, b.y, c.x, c.y, d.x, d.y};
  }
}

__global__ __launch_bounds__(256) void conv_b_kernel(
    const int* __restrict__ Qw, const float* __restrict__ Sc,
    f16* __restrict__ Wf)
{
  const int o = blockIdx.x;
  const int t = threadIdx.x;
  const float s = Sc[o];
  const int* q = Qw + (size_t)o * K_DIM + t * 16;
  f16* w = Wf + (size_t)o * K_DIM + t * 16;
  #pragma unroll
  for (int h = 0; h < 2; ++h) {
    int4 u0 = *(const int4*)(q + h * 8);
    int4 u1 = *(const int4*)(q + h * 8 + 4);
    f16x2 a = cvt2((float)u0.x * s, (float)u0.y * s);
    f16x2 b = cvt2((float)u0.z * s, (float)u0.w * s);
    f16x2 c = cvt2((float)u1.x * s, (float)u1.y * s);
    f16x2 d = cvt2((float)u1.z * s, (float)u1.w * s);
    *(f16x8*)(w + h * 8) = (f16x8){a.x, a.y, b.x, b.y, c.x, c.y, d.x, d.y};
  }
}

// ---------------- main GEMM ----------------

#define BARX() __builtin_amdgcn_s_barrier()
#define SCHED0() __builtin_amdgcn_sched_barrier(0)
#define LGKM(n) do { asm volatile("s_waitcnt lgkmcnt(" #n ")" ::: "memory"); \
                     __builtin_amdgcn_sched_barrier(0); } while (0)
#define VMW(n) asm volatile("s_waitcnt vmcnt(" #n ")" ::: "memory")

// 8 ds_read_b128: A-half qm -> dst[4][2]
#define READ_A2(buf_, qm, dst) do { \
  const char* _b = (const char*)&As[buf_][qm][0]; \
  _Pragma("unroll") \
  for (int j = 0; j < 4; ++j) { \
    const int _lr = (2 * j + wm) * 16 + fr; \
    dst[j][0] = *(const f16x8*)(_b + _lr * 128 + (((qk    ) ^ x7) << 4)); \
    dst[j][1] = *(const f16x8*)(_b + _lr * 128 + (((qk + 4) ^ x7) << 4)); \
  } } while (0)

// 4 ds_read_b128: B-half qn -> dst[2][2]
#define READ_B2(buf_, qn, dst) do { \
  const char* _b = (const char*)&Bs[buf_][qn][0]; \
  _Pragma("unroll") \
  for (int nl = 0; nl < 2; ++nl) { \
    const int _lr = nl * 64 + wn * 16 + fr; \
    dst[nl][0] = *(const f16x8*)(_b + _lr * 128 + (((qk    ) ^ x7) << 4)); \
    dst[nl][1] = *(const f16x8*)(_b + _lr * 128 + (((qk + 4) ^ x7) << 4)); \
  } } while (0)

// 16 MFMA for quadrant (qm, qn) using frag buffers A_, B_
#define MFMAQ(qm, qn, A_, B_) do { \
  __builtin_amdgcn_s_setprio(1); \
  _Pragma("unroll") \
  for (int j = 0; j < 4; ++j) \
    _Pragma("unroll") \
    for (int nl = 0; nl < 2; ++nl) { \
      acc[(qm)*4 + j][(qn)*2 + nl] = __builtin_amdgcn_mfma_f32_16x16x32_f16( \
          A_[j][0], B_[nl][0], acc[(qm)*4 + j][(qn)*2 + nl], 0, 0, 0); \
      acc[(qm)*4 + j][(qn)*2 + nl] = __builtin_amdgcn_mfma_f32_16x16x32_f16( \
          A_[j][1], B_[nl][1], acc[(qm)*4 + j][(qn)*2 + nl], 0, 0, 0); \
    } \
  __builtin_amdgcn_s_setprio(0); } while (0)

// stage one 128x64 f16 half-tile: 2 x global_load_lds(16B), linear LDS dest,
// inverse-swizzled global source (slot^(row&7))
#define STAGE(dstHalf, srcPanel, h, ktn) do { \
  _Pragma("unroll") \
  for (int _i = 0; _i < 2; ++_i) { \
    const f16* _g = (srcPanel) + (size_t)((h) * 128 + _i * 64 + st_row) * K_DIM \
                    + (ktn) * 64 + st_slot * 8; \
    char* _l = (char*)(dstHalf) + _i * 8192 + wid * 1024; \
    __builtin_amdgcn_global_load_lds( \
        (const __attribute__((address_space(1))) void*)_g, \
        (__attribute__((address_space(3))) void*)_l, 16, 0, 0); \
  } } while (0)

__global__ __launch_bounds__(512, 2) void w8a16_gemm_f16_kernel(
    const f16* __restrict__ Af,   // [M][K]
    const f16* __restrict__ Wf,   // [N][K], scale folded
    float* __restrict__ Out)      // [M][N]
{
  // halves: [buf][half][128 rows][64 f16]; 16B slots XOR-swizzled by (row&7)
  __shared__ __align__(16) f16 As[2][2][128 * 64];
  __shared__ __align__(16) f16 Bs[2][2][128 * 64];

  const int t    = threadIdx.x;
  const int lane = t & 63;
  const int wid  = t >> 6;       // 0..7
  const int wm   = wid >> 2;     // 0..1
  const int wn   = wid & 3;      // 0..3
  const int fr   = lane & 15;
  const int qk   = lane >> 4;
  const int x7   = fr & 7;

  const int st_row  = t >> 3;
  const int st_slot = (t & 7) ^ ((t >> 3) & 7);

  // XCD swizzle: 512 blocks, %8==0 -> simple bijective form
  const int bid = blockIdx.x;
  const int swz = (bid & 7) * 64 + (bid >> 3);
  const int tn  = swz & 15;      // 16 N-tiles
  const int tm  = swz >> 4;      // 32 M-tiles

  const f16* aSrc = Af + (size_t)tm * BM * K_DIM;
  const f16* bSrc = Wf + (size_t)tn * BN * K_DIM;

  f32x4 acc[8][4] = {};
  f16x8 af0[4][2], af1[4][2], bf0[2][2], bf1[2][2];

  // prologue: stage K-tile 0 fully; seal; issue boundary reads (A0,B0)
  STAGE(&As[0][0][0], aSrc, 0, 0);
  STAGE(&Bs[0][0][0], bSrc, 0, 0);
  STAGE(&Bs[0][1][0], bSrc, 1, 0);
  STAGE(&As[0][1][0], aSrc, 1, 0);
  VMW(0);
  BARX();
  SCHED0();
  READ_A2(0, 0, af0);
  READ_B2(0, 0, bf0);

  for (int kt = 0; kt < NKT; ++kt) {
    const int  buf  = kt & 1;
    const int  nbuf = buf ^ 1;
    const bool more = (kt + 1) < NKT;

    // p1: issue B1 reads; stage HA0',HB0',HB1'; MFMA q00 (A0,B0 landed)
    READ_B2(buf, 1, bf1);
    if (more) {
      STAGE(&As[nbuf][0][0], aSrc, 0, kt + 1);
      STAGE(&Bs[nbuf][0][0], bSrc, 0, kt + 1);
      STAGE(&Bs[nbuf][1][0], bSrc, 1, kt + 1);
    }
    LGKM(4);
    MFMAQ(0, 0, af0, bf0);
    BARX();

    // p2: issue A1 reads; stage HA1'; MFMA q01 (B1 landed)
    READ_A2(buf, 1, af1);
    if (more) STAGE(&As[nbuf][1][0], aSrc, 1, kt + 1);
    LGKM(8);
    MFMAQ(0, 1, af0, bf1);
    BARX();

    // p3: MFMA q10 (A1 landed)
    LGKM(0);
    MFMAQ(1, 0, af1, bf0);
    BARX();

    // p4: seal nbuf staging; issue boundary reads (A0',B0') under q11
    if (more) {
      VMW(0);
      BARX();
      SCHED0();
      READ_A2(nbuf, 0, af0);
      READ_B2(nbuf, 0, bf0);
    }
    MFMAQ(1, 1, af1, bf1);
  }

  // epilogue: C/D col = lane&15, row = (lane>>4)*4 + reg
  const int fq = lane >> 4;
  #pragma unroll
  for (int mi = 0; mi < 8; ++mi) {
    const size_t row = (size_t)tm * BM + (mi * 2 + wm) * 16 + fq * 4;
    #pragma unroll
    for (int ni = 0; ni < 4; ++ni) {
      const size_t col = (size_t)tn * BN + ni * 64 + wn * 16 + fr;
      #pragma unroll
      for (int r = 0; r < 4; ++r)
        Out[(row + r) * N_DIM + col] = acc[mi][ni][r];
    }
  }
}

// ---------------- fallback (round-3 verified path) ----------------

__global__ __launch_bounds__(256) void w8a16_gemm_fb_kernel(
    const float* __restrict__ A, const int* __restrict__ Qw,
    const float* __restrict__ Sc, float* __restrict__ Out)
{
  __shared__ __align__(16) float Asf[2][128 * 32];
  __shared__ __align__(16) f16 Bsf[2][128][32];

  const int t = threadIdx.x, lane = t & 63, wid = t >> 6;
  const int wr = wid >> 1, wc = wid & 1;
  const int nwg = gridDim.x, cpx = nwg >> 3, bid = blockIdx.x;
  const int swz = (bid & 7) * cpx + (bid >> 3);
  const int tn = swz & 31, tm = swz >> 5;
  const size_t a_base = (size_t)tm * 128 * K_DIM;
  const size_t b_base = (size_t)tn * 128 * K_DIM;
  f32x4 acc[4][4] = {};
  const int a_r = t >> 3;
  const int a_slog = (t & 7) ^ ((t >> 3) & 7);

  auto stageA = [&](int buf, int kt) {
    #pragma unroll
    for (int c = 0; c < 4; ++c) {
      const float* g = A + a_base + (size_t)(c * 32 + a_r) * K_DIM + kt * 32 + a_slog * 4;
      char* l = (char*)&Asf[buf][0] + c * 4096 + wid * 1024;
      __builtin_amdgcn_global_load_lds(
          (const __attribute__((address_space(1))) void*)g,
          (__attribute__((address_space(3))) void*)l, 16, 0, 0);
    }
  };
  const int b_r = t >> 3, b_col = (t & 7) * 4;
  auto loadB = [&](int kt, int4* v) {
    #pragma unroll
    for (int c = 0; c < 4; ++c)
      v[c] = *(const int4*)(Qw + b_base + (size_t)(c * 32 + b_r) * K_DIM + kt * 32 + b_col);
  };
  auto writeB = [&](int buf, const int4* v) {
    #pragma unroll
    for (int c = 0; c < 4; ++c) {
      f16x2 lo = cvt2((float)v[c].x, (float)v[c].y);
      f16x2 hi = cvt2((float)v[c].z, (float)v[c].w);
      *(f16x2*)&Bsf[buf][c * 32 + b_r][b_col] = lo;
      *(f16x2*)&Bsf[buf][c * 32 + b_r][b_col + 2] = hi;
    }
  };
  auto compute = [&](int buf) {
    const int fr2 = lane & 15, q = lane >> 4;
    f16x8 af2[4], bf2[4];
    #pragma unroll
    for (int i = 0; i < 4; ++i) {
      const int r = wr * 64 + i * 16 + fr2;
      const float* base = &Asf[buf][0] + r * 32;
      const int s0 = q * 2;
      f32x4 a0 = *(const f32x4*)(base + ((s0 ^ (r & 7)) * 4));
      f32x4 a1 = *(const f32x4*)(base + (((s0 + 1) ^ (r & 7)) * 4));
      f16x2 p0 = cvt2(a0.x, a0.y), p1 = cvt2(a0.z, a0.w);
      f16x2 p2 = cvt2(a1.x, a1.y), p3 = cvt2(a1.z, a1.w);
      af2[i] = (f16x8){p0.x, p0.y, p1.x, p1.y, p2.x, p2.y, p3.x, p3.y};
      bf2[i] = *(const f16x8*)&Bsf[buf][wc * 64 + i * 16 + fr2][q * 8];
    }
    #pragma unroll
    for (int mi = 0; mi < 4; ++mi)
      #pragma unroll
      for (int ni = 0; ni < 4; ++ni)
        acc[mi][ni] = __builtin_amdgcn_mfma_f32_16x16x32_f16(
            af2[mi], bf2[ni], acc[mi][ni], 0, 0, 0);
  };

  { int4 b0[4]; stageA(0, 0); loadB(0, b0); writeB(0, b0); }
  __syncthreads();
  for (int kt = 0; kt < K_DIM / 32; ++kt) {
    const int buf = kt & 1;
    const bool more = (kt + 1) < K_DIM / 32;
    int4 nb[4];
    if (more) { stageA(buf ^ 1, kt + 1); loadB(kt + 1, nb); }
    compute(buf);
    if (more) writeB(buf ^ 1, nb);
    __syncthreads();
  }
  const int fr2 = lane & 15, fq = lane >> 4;
  const int cb = tn * 128 + wc * 64 + fr2;
  const int rb = tm * 128 + wr * 64 + fq * 4;
  #pragma unroll
  for (int ni = 0; ni < 4; ++ni) {
    const float s = Sc[cb + ni * 16];
    #pragma unroll
    for (int mi = 0; mi < 4; ++mi)
      #pragma unroll
      for (int r = 0; r < 4; ++r)
        Out[(size_t)(rb + mi * 16 + r) * N_DIM + (cb + ni * 16)] =
            acc[mi][ni][r] * s;
  }
}

extern "C" void kernel_launch(void* const* d_in, const int* in_sizes, int n_in,
                              void* d_out, int out_size, void* d_ws, size_t ws_size,
                              hipStream_t stream) {
  const float* A  = (const float*)d_in[0];
  const int*   Qw = (const int*)d_in[1];
  const float* Sc = (const float*)d_in[2];
  float*       Out = (float*)d_out;

  const size_t a_bytes = (size_t)M_DIM * K_DIM * sizeof(f16);  // 64 MB
  const size_t w_bytes = (size_t)N_DIM * K_DIM * sizeof(f16);  // 32 MB

  if (ws_size >= a_bytes + w_bytes) {
    f16* Af = (f16*)d_ws;
    f16* Wf = (f16*)((char*)d_ws + a_bytes);
    conv_a_kernel<<<2048, 256, 0, stream>>>(A, Af);
    conv_b_kernel<<<N_DIM, 256, 0, stream>>>(Qw, Sc, Wf);
    dim3 grid((M_DIM / BM) * (N_DIM / BN));  // 32*16 = 512
    w8a16_gemm_f16_kernel<<<grid, 512, 0, stream>>>(Af, Wf, Out);
  } else {
    dim3 grid((M_DIM / 128) * (N_DIM / 128));
    w8a16_gemm_fb_kernel<<<grid, 256, 0, stream>>>(A, Qw, Sc, Out);
  }
}